// Round 7
// baseline (168.006 us; speedup 1.0000x reference)
//
#include <hip/hip_runtime.h>
#include <hip/hip_bf16.h>

// Problem constants (match reference)
#define B_   2
#define S_   2048
#define D_   512
#define H_   8
#define DK_  64
#define M_   (B_*S_)   // 4096 rows in the [B*S, D] view

typedef float  floatx4  __attribute__((ext_vector_type(4)));
typedef float  floatx16 __attribute__((ext_vector_type(16)));
typedef __bf16 bf16x8   __attribute__((ext_vector_type(8)));

#define MFMA16x16x32(a,b,c) __builtin_amdgcn_mfma_f32_16x16x32_bf16((a),(b),(c),0,0,0)
#define MFMA32x32x16(a,b,c) __builtin_amdgcn_mfma_f32_32x32x16_bf16((a),(b),(c),0,0,0)

// async global->LDS, 16 B per lane; LDS dest = wave-uniform base + lane*16
static __device__ __forceinline__ void load_lds16(const void* g, void* l) {
  __builtin_amdgcn_global_load_lds(
      (const __attribute__((address_space(1))) void*)g,
      (__attribute__((address_space(3))) void*)l,
      16, 0, 0);
}

static __device__ __forceinline__ bf16x8 cvt8(float4 a, float4 b) {
  bf16x8 r;
  r[0]=(__bf16)a.x; r[1]=(__bf16)a.y; r[2]=(__bf16)a.z; r[3]=(__bf16)a.w;
  r[4]=(__bf16)b.x; r[5]=(__bf16)b.y; r[6]=(__bf16)b.z; r[7]=(__bf16)b.w;
  return r;
}

// ---------------------------------------------------------------------------
// Kernel 0: one-shot fp32 -> bf16 convert of X (q,k,v) and W (q,k,v,o).
// (harness-verified, unchanged)
// ---------------------------------------------------------------------------
__global__ __launch_bounds__(256) void cvt_inputs(
    const float* __restrict__ s0, const float* __restrict__ s1,
    const float* __restrict__ s2, const float* __restrict__ s3,
    const float* __restrict__ s4, const float* __restrict__ s5,
    const float* __restrict__ s6,
    __bf16* __restrict__ d0, __bf16* __restrict__ d1,
    __bf16* __restrict__ d2, __bf16* __restrict__ d3,
    __bf16* __restrict__ d4, __bf16* __restrict__ d5,
    __bf16* __restrict__ d6)
{
  const int t = blockIdx.y;
  const float* src = (t==0)?s0:(t==1)?s1:(t==2)?s2:(t==3)?s3:(t==4)?s4:(t==5)?s5:s6;
  __bf16*      dst = (t==0)?d0:(t==1)?d1:(t==2)?d2:(t==3)?d3:(t==4)?d4:(t==5)?d5:d6;
  const int nu = (t < 3) ? (M_*D_/8) : (D_*D_/8);   // 8-element units
  const int stride = gridDim.x * 256;
  for (int u = blockIdx.x*256 + threadIdx.x; u < nu; u += stride) {
    const float4* p = (const float4*)src + (size_t)u*2;
    float4 x0 = p[0], x1 = p[1];
    *(bf16x8*)(dst + (size_t)u*8) = cvt8(x0, x1);
  }
}

// ---------------------------------------------------------------------------
// K / Vt global layouts (chunk-major, XOR-swizzled row-major):
//   K  chunk c: elem(key,dk) at c*4096 + key*64 + (dk  ^ ((key&7)<<3))
//   Vt chunk c: elem(d,key)  at c*4096 + d*64   + (key ^ ((d  &7)<<3))
// ---------------------------------------------------------------------------

// ---------------------------------------------------------------------------
// Kernel 1: QKV projection, 128x64 tile, BK=32, bf16 inputs staged via
// global_load_lds into linear LDS, double-buffered.  (harness-verified,
// unchanged from round 2.)  grid = (M/128, D/64, 3).
// ---------------------------------------------------------------------------
__global__ __launch_bounds__(256) void proj_qkv(
    const __bf16* __restrict__ Xq, const __bf16* __restrict__ Xk,
    const __bf16* __restrict__ Xv,
    const __bf16* __restrict__ Wqb, const __bf16* __restrict__ Wkb,
    const __bf16* __restrict__ Wvb,
    const float* __restrict__ bq, const float* __restrict__ bk,
    const float* __restrict__ bv,
    __bf16* __restrict__ Qb, __bf16* __restrict__ Kb, __bf16* __restrict__ Vtb)
{
  __shared__ __align__(16) __bf16 smem[12288];

  const int z = blockIdx.z;
  const __bf16* X = (z==0) ? Xq  : (z==1) ? Xk  : Xv;
  const __bf16* W = (z==0) ? Wqb : (z==1) ? Wkb : Wvb;
  const float* bias = (z==0) ? bq : (z==1) ? bk : bv;

  const int m0 = blockIdx.x * 128;
  const int n0 = blockIdx.y * 64;      // == head*64
  const int tid  = threadIdx.x;
  const int w    = tid >> 6;
  const int lane = tid & 63;
  const int lcol = lane & 15;
  const int quad = lane >> 4;

  auto stage = [&](int bsel, int k0) {
#pragma unroll
    for (int j = 0; j < 2; ++j) {
      const int u = j*256 + tid;               // 16 B unit
      const int row = u >> 2, c8 = (u & 3)*8;
      load_lds16(X + (size_t)(m0 + row)*D_ + k0 + c8,
                 smem + bsel*4096 + u*8);
    }
    {
      const int u = tid;
      const int row = u >> 2, c8 = (u & 3)*8;
      load_lds16(W + (size_t)(n0 + row)*D_ + k0 + c8,
                 smem + 8192 + bsel*2048 + u*8);
    }
  };

  floatx4 zero = {0.f,0.f,0.f,0.f};
  floatx4 acc[2][4] = {{zero,zero,zero,zero},{zero,zero,zero,zero}};

  stage(0, 0);
  for (int it = 0; it < 16; ++it) {
    __syncthreads();                            // drains vmcnt: buf(it&1) ready
    if (it + 1 < 16) stage((it+1)&1, (it+1)*32);
    const __bf16* ab = smem + (it&1)*4096;
    const __bf16* bb = smem + 8192 + (it&1)*2048;
    bf16x8 af[2], bf[4];
#pragma unroll
    for (int mr = 0; mr < 2; ++mr)
      af[mr] = *(const bf16x8*)(ab + (w*32 + mr*16 + lcol)*32 + quad*8);
#pragma unroll
    for (int nt = 0; nt < 4; ++nt)
      bf[nt] = *(const bf16x8*)(bb + (nt*16 + lcol)*32 + quad*8);
#pragma unroll
    for (int mr = 0; mr < 2; ++mr)
#pragma unroll
      for (int nt = 0; nt < 4; ++nt)
        acc[mr][nt] = MFMA16x16x32(af[mr], bf[nt], acc[mr][nt]);
  }

  // ---- epilogue: scatter C frags into smem[0,8192) in output layout ----
  __syncthreads();
#pragma unroll
  for (int mr = 0; mr < 2; ++mr) {
#pragma unroll
    for (int nt = 0; nt < 4; ++nt) {
      const int dk = nt*16 + lcol;             // n & 63 (n0 head-aligned)
      const float bias_n = bias[n0 + dk];
#pragma unroll
      for (int r = 0; r < 4; ++r) {
        const int row = w*32 + mr*16 + quad*4 + r;   // m & 127
        const int klo = row & 63, ch = row >> 6;
        const float val = acc[mr][nt][r] + bias_n;
        int off;
        if (z == 0) {
          off = row*64 + dk;                                    // Q plain
        } else if (z == 1) {
          off = ch*4096 + klo*64 + (dk ^ ((klo & 7) << 3));     // K swz
        } else {
          off = ch*4096 + dk*64 + (klo ^ ((dk & 7) << 3));      // Vt swz
        }
        smem[off] = (__bf16)val;
      }
    }
  }
  __syncthreads();

  // ---- coalesced copy-out: one contiguous 16 KB piece ----
  __bf16* dst = (z==0) ? Qb : (z==1) ? Kb : Vtb;
  const int bb2 = m0 >> 11;            // batch
  const int hh  = n0 >> 6;             // head
  const size_t base = ((size_t)(bb2*H_ + hh))*(S_*DK_) + (size_t)(m0 & 2047)*64;
#pragma unroll
  for (int i = 0; i < 4; ++i) {
    const int u = i*256 + tid;         // 16B unit, 0..1023
    *(bf16x8*)(dst + base + u*8) = *(const bf16x8*)(smem + u*8);
  }
}

// ---------------------------------------------------------------------------
// Kernel 2: causal attention, swapped-QK 32x32, NO split-K.
// One block per 128-row q-tile: grid = (16, H, B), heavy tiles first.
// Inner body = round-2 harness-verified code.  Epilogue normalizes in-kernel
// (per-wave L broadcast via LDS) and writes final O directly to attnb.
// Pb / Lb eliminated (~30 MB HBM bookkeeping removed).
// ---------------------------------------------------------------------------
__global__ __launch_bounds__(256) void attn_fwd(
    const __bf16* __restrict__ Qb, const __bf16* __restrict__ Kb,
    const __bf16* __restrict__ Vtb, __bf16* __restrict__ attnb)
{
  __shared__ __align__(16) __bf16 smem[16384];   // 32 KB: K/V dbuf, then O
  float* Lsh = (float*)(smem + 8192);            // 512 B, used after the loop

  const int tid  = threadIdx.x;
  const int w    = tid >> 6;
  const int lane = tid & 63;
  const int l31  = lane & 31;
  const int hi   = lane >> 5;
  const int hh = blockIdx.y;
  const int bb = blockIdx.z;

  const int t  = 15 - blockIdx.x;      // heavy tiles dispatch first
  const int nc = 2*t + 2;              // chunks 0..nc-1 cover keys <= q_max

  const int qr0    = t*128 + w*32;
  const int q_lane = qr0 + l31;

  const __bf16* Qp = Qb  + (size_t)(bb*H_ + hh) * S_ * DK_;
  const __bf16* Kp = Kb  + (size_t)(bb*H_ + hh) * S_ * DK_;
  const __bf16* Vp = Vtb + (size_t)(bb*H_ + hh) * DK_ * S_;

  // Q as B-operand fragments: lane holds Q[q=l31][ks*16 + hi*8 + j]
  bf16x8 qf[4];
#pragma unroll
  for (int ks = 0; ks < 4; ++ks)
    qf[ks] = *(const bf16x8*)(Qp + (size_t)q_lane*DK_ + ks*16 + hi*8);

  floatx16 o0 = (floatx16)0.f, o1 = (floatx16)0.f;  // O[q][d<32], O[q][d>=32]
  float lsum = 0.f;

  auto stage_chunk = [&](int bsel, int c) {
    const char* ksrc = (const char*)(Kp + (size_t)c * 4096);
    const char* vsrc = (const char*)(Vp + (size_t)c * 4096);
    char* kd = (char*)smem + bsel*8192;
    char* vd = (char*)smem + 16384 + bsel*8192;
#pragma unroll
    for (int j = 0; j < 2; ++j) {
      const int off = j*4096 + tid*16;
      load_lds16(ksrc + off, kd + off);
      load_lds16(vsrc + off, vd + off);
    }
  };

  auto mkpa = [&](float a0,float a1,float a2,float a3,
                  float b0,float b1,float b2,float b3) -> bf16x8 {
    unsigned x0,x1,y0,y1;
    asm("v_cvt_pk_bf16_f32 %0, %1, %2" : "=v"(x0) : "v"(a0), "v"(a1));
    asm("v_cvt_pk_bf16_f32 %0, %1, %2" : "=v"(x1) : "v"(a2), "v"(a3));
    asm("v_cvt_pk_bf16_f32 %0, %1, %2" : "=v"(y0) : "v"(b0), "v"(b1));
    asm("v_cvt_pk_bf16_f32 %0, %1, %2" : "=v"(y1) : "v"(b2), "v"(b3));
    asm("v_permlane32_swap_b32 %0, %1" : "+v"(x0), "+v"(y0));
    asm("v_permlane32_swap_b32 %0, %1" : "+v"(x1), "+v"(y1));
    union { unsigned u[4]; bf16x8 v; } r;
    r.u[0] = x0; r.u[1] = x1; r.u[2] = y0; r.u[3] = y1;
    return r.v;
  };

  const float SC = 0.18033688011112042f;   // log2(e)/sqrt(DK)

  stage_chunk(0, 0);
  for (int c = 0; c < nc; ++c) {
    __syncthreads();                       // chunk c staged
    if (c + 1 < nc) stage_chunk((c + 1)&1, c+1);
    const int bsel = c & 1;
    const __bf16* kb = smem + bsel*4096;
    const __bf16* vb = smem + 8192 + bsel*4096;

    if (c*64 <= qr0 + 31) {                // wave has unmasked work here
      // ---- QK^T swapped: s[key][q], key blocks 0/1 ----
      floatx16 s0 = (floatx16)0.f, s1 = (floatx16)0.f;
#pragma unroll
      for (int ks = 0; ks < 4; ++ks) {
        const int csw = (ks*16 + hi*8) ^ ((l31 & 7) << 3);
        bf16x8 kf0 = *(const bf16x8*)(kb + l31*64 + csw);
        bf16x8 kf1 = *(const bf16x8*)(kb + (32 + l31)*64 + csw);
        s0 = MFMA32x32x16(kf0, qf[ks], s0);
        s1 = MFMA32x32x16(kf1, qf[ks], s1);
      }

      // ---- softmax (no max subtraction; scores O(1)) + causal mask ----
      const bool edge = (c*64 + 63 > qr0);
      if (edge) {
#pragma unroll
        for (int r = 0; r < 16; ++r) {
          const int koff = 8*(r>>2) + 4*hi + (r&3);
          float v0 = exp2f(s0[r] * SC);
          float v1 = exp2f(s1[r] * SC);
          s0[r] = (c*64 + koff      <= q_lane) ? v0 : 0.f;
          s1[r] = (c*64 + 32 + koff <= q_lane) ? v1 : 0.f;
        }
      } else {
#pragma unroll
        for (int r = 0; r < 16; ++r) {
          s0[r] = exp2f(s0[r] * SC);
          s1[r] = exp2f(s1[r] * SC);
        }
      }
#pragma unroll
      for (int r = 0; r < 16; ++r) lsum += s0[r] + s1[r];

      bf16x8 pa[4];
      pa[0] = mkpa(s0[0],s0[1],s0[2],s0[3],s0[4],s0[5],s0[6],s0[7]);
      pa[1] = mkpa(s0[8],s0[9],s0[10],s0[11],s0[12],s0[13],s0[14],s0[15]);
      pa[2] = mkpa(s1[0],s1[1],s1[2],s1[3],s1[4],s1[5],s1[6],s1[7]);
      pa[3] = mkpa(s1[8],s1[9],s1[10],s1[11],s1[12],s1[13],s1[14],s1[15]);

      // ---- PV: O += P * V  (B-frags from swizzled Vt tile) ----
#pragma unroll
      for (int ks = 0; ks < 4; ++ks) {
        const int csw0 = (ks*16 + hi*8) ^ ((l31 & 7) << 3);
        bf16x8 vf0 = *(const bf16x8*)(vb + l31*64 + csw0);
        bf16x8 vf1 = *(const bf16x8*)(vb + (32 + l31)*64 + csw0);
        o0 = MFMA32x32x16(pa[ks], vf0, o0);
        o1 = MFMA32x32x16(pa[ks], vf1, o1);
      }
    }
  }

  // ---- epilogue: normalize in-kernel, write final O to attnb ----
  __syncthreads();                          // all waves done with K/V bufs
  const float ltot = lsum + __shfl_xor(lsum, 32);   // L[q=l31], both halves
  if (lane < 32) Lsh[w*32 + l31] = ltot;
  asm volatile("s_waitcnt lgkmcnt(0)" ::: "memory");  // wave-local L ready
  __syncthreads();                          // Lsh visible block-wide

  __bf16* ob = smem;                        // [128][64] bf16 (16 KB)
#pragma unroll
  for (int r = 0; r < 16; ++r) {
    const int qloc = 8*(r>>2) + 4*hi + (r&3);
    const float rinv = 1.0f / Lsh[w*32 + qloc];   // broadcast read (free)
    ob[(w*32 + qloc)*64 + l31]      = (__bf16)(o0[r] * rinv);
    ob[(w*32 + qloc)*64 + 32 + l31] = (__bf16)(o1[r] * rinv);
  }
  __syncthreads();

  // coalesced copy to attnb [B,S,D]: 128 rows x 128 B (this head's column)
  __bf16* adst = attnb + ((size_t)(bb*S_ + t*128))*D_ + hh*DK_;
#pragma unroll
  for (int i = 0; i < 4; ++i) {
    const int u = i*256 + tid;              // 16 B unit, 0..1023
    const int row = u >> 3, grp = u & 7;
    *(bf16x8*)(adst + (size_t)row*D_ + grp*8) = *(const bf16x8*)(smem + u*8);
  }
}

// ---------------------------------------------------------------------------
// Kernel 3: output projection — pure GEMM, 128x64 tile, BK=32, both operands
// via global_load_lds (same structure as proj_qkv), direct fp32 C-write.
// grid = (M/128, D/64) = 256 blocks.
// ---------------------------------------------------------------------------
__global__ __launch_bounds__(256) void proj_out(
    const __bf16* __restrict__ attnb, const __bf16* __restrict__ Wob,
    const float* __restrict__ bo, float* __restrict__ out)
{
  __shared__ __align__(16) __bf16 smem[12288];

  const int m0 = blockIdx.x * 128;
  const int n0 = blockIdx.y * 64;
  const int tid  = threadIdx.x;
  const int w    = tid >> 6;
  const int lane = tid & 63;
  const int lcol = lane & 15;
  const int quad = lane >> 4;

  auto stage = [&](int bsel, int k0) {
#pragma unroll
    for (int j = 0; j < 2; ++j) {
      const int u = j*256 + tid;               // 16 B unit
      const int row = u >> 2, c8 = (u & 3)*8;
      load_lds16(attnb + (size_t)(m0 + row)*D_ + k0 + c8,
                 smem + bsel*4096 + u*8);
    }
    {
      const int u = tid;
      const int row = u >> 2, c8 = (u & 3)*8;
      load_lds16(Wob + (size_t)(n0 + row)*D_ + k0 + c8,
                 smem + 8192 + bsel*2048 + u*8);
    }
  };

  floatx4 zero = {0.f,0.f,0.f,0.f};
  floatx4 acc[2][4] = {{zero,zero,zero,zero},{zero,zero,zero,zero}};

  stage(0, 0);
  for (int it = 0; it < 16; ++it) {
    __syncthreads();                            // drains vmcnt: buf(it&1) ready
    if (it + 1 < 16) stage((it+1)&1, (it+1)*32);
    const __bf16* ab = smem + (it&1)*4096;
    const __bf16* bb = smem + 8192 + (it&1)*2048;
    bf16x8 af[2], bf[4];
#pragma unroll
    for (int mr = 0; mr < 2; ++mr)
      af[mr] = *(const bf16x8*)(ab + (w*32 + mr*16 + lcol)*32 + quad*8);
#pragma unroll
    for (int nt = 0; nt < 4; ++nt)
      bf[nt] = *(const bf16x8*)(bb + (nt*16 + lcol)*32 + quad*8);
#pragma unroll
    for (int mr = 0; mr < 2; ++mr)
#pragma unroll
      for (int nt = 0; nt < 4; ++nt)
        acc[mr][nt] = MFMA16x16x32(af[mr], bf[nt], acc[mr][nt]);
  }

  // direct C-write: fp32, 64 B contiguous per 16-lane group
#pragma unroll
  for (int mr = 0; mr < 2; ++mr) {
#pragma unroll
    for (int nt = 0; nt < 4; ++nt) {
      const int n = n0 + nt*16 + lcol;
      const float bias_n = bo[n];
#pragma unroll
      for (int r = 0; r < 4; ++r) {
        const int row = w*32 + mr*16 + quad*4 + r;
        out[(size_t)(m0 + row) * D_ + n] = acc[mr][nt][r] + bias_n;
      }
    }
  }
}

// ---------------------------------------------------------------------------
extern "C" void kernel_launch(void* const* d_in, const int* in_sizes, int n_in,
                              void* d_out, int out_size, void* d_ws, size_t ws_size,
                              hipStream_t stream) {
  const float* q_in = (const float*)d_in[0];
  const float* k_in = (const float*)d_in[1];
  const float* v_in = (const float*)d_in[2];
  // d_in[3] = mask (causal tril) — implied by the kernel, unused
  const float* Wq = (const float*)d_in[4];
  const float* bq = (const float*)d_in[5];
  const float* Wk = (const float*)d_in[6];
  const float* bk = (const float*)d_in[7];
  const float* Wv = (const float*)d_in[8];
  const float* bv = (const float*)d_in[9];
  const float* Wo = (const float*)d_in[10];
  const float* bo = (const float*)d_in[11];
  float* out = (float*)d_out;

  __bf16* ws    = (__bf16*)d_ws;
  __bf16* Qb    = ws;                  // [B,H,S,DK] plain
  __bf16* Kb    = ws + 1*2097152;      // chunk-major, swizzled
  __bf16* Vtb   = ws + 2*2097152;      // chunk-major, swizzled (transposed)
  __bf16* attnb = ws + 3*2097152;      // [B,S,D] final attention output

  // bf16 copies of inputs (written by cvt_inputs each launch)
  __bf16* Xqb = ws + 4*2097152;
  __bf16* Xkb = Xqb + 2097152;
  __bf16* Xvb = Xkb + 2097152;
  __bf16* Wqb = Xvb + 2097152;
  __bf16* Wkb = Wqb + 262144;
  __bf16* Wvb = Wkb + 262144;
  __bf16* Wob = Wvb + 262144;

  cvt_inputs<<<dim3(512, 7, 1), dim3(256), 0, stream>>>(
      q_in, k_in, v_in, Wq, Wk, Wv, Wo,
      Xqb, Xkb, Xvb, Wqb, Wkb, Wvb, Wob);

  proj_qkv<<<dim3(M_/128, D_/64, 3), dim3(256), 0, stream>>>(
      Xqb, Xkb, Xvb, Wqb, Wkb, Wvb, bq, bk, bv, Qb, Kb, Vtb);

  attn_fwd<<<dim3(16, H_, B_), dim3(256), 0, stream>>>(
      Qb, Kb, Vtb, attnb);

  proj_out<<<dim3(M_/128, D_/64), dim3(256), 0, stream>>>(
      attnb, Wob, bo, out);
}

// Round 8
// 158.240 us; speedup vs baseline: 1.0617x; 1.0617x over previous
//
#include <hip/hip_runtime.h>
#include <hip/hip_bf16.h>

// Problem constants (match reference)
#define B_   2
#define S_   2048
#define D_   512
#define H_   8
#define DK_  64
#define M_   (B_*S_)   // 4096 rows in the [B*S, D] view

typedef float  floatx4  __attribute__((ext_vector_type(4)));
typedef float  floatx16 __attribute__((ext_vector_type(16)));
typedef __bf16 bf16x8   __attribute__((ext_vector_type(8)));

#define MFMA16x16x32(a,b,c) __builtin_amdgcn_mfma_f32_16x16x32_bf16((a),(b),(c),0,0,0)
#define MFMA32x32x16(a,b,c) __builtin_amdgcn_mfma_f32_32x32x16_bf16((a),(b),(c),0,0,0)

// async global->LDS, 16 B per lane; LDS dest = wave-uniform base + lane*16
static __device__ __forceinline__ void load_lds16(const void* g, void* l) {
  __builtin_amdgcn_global_load_lds(
      (const __attribute__((address_space(1))) void*)g,
      (__attribute__((address_space(3))) void*)l,
      16, 0, 0);
}

static __device__ __forceinline__ bf16x8 cvt8(float4 a, float4 b) {
  bf16x8 r;
  r[0]=(__bf16)a.x; r[1]=(__bf16)a.y; r[2]=(__bf16)a.z; r[3]=(__bf16)a.w;
  r[4]=(__bf16)b.x; r[5]=(__bf16)b.y; r[6]=(__bf16)b.z; r[7]=(__bf16)b.w;
  return r;
}

// ---------------------------------------------------------------------------
// Kernel 0: one-shot fp32 -> bf16 convert of X (q,k,v) and W (q,k,v,o).
// (harness-verified, unchanged)
// ---------------------------------------------------------------------------
__global__ __launch_bounds__(256) void cvt_inputs(
    const float* __restrict__ s0, const float* __restrict__ s1,
    const float* __restrict__ s2, const float* __restrict__ s3,
    const float* __restrict__ s4, const float* __restrict__ s5,
    const float* __restrict__ s6,
    __bf16* __restrict__ d0, __bf16* __restrict__ d1,
    __bf16* __restrict__ d2, __bf16* __restrict__ d3,
    __bf16* __restrict__ d4, __bf16* __restrict__ d5,
    __bf16* __restrict__ d6)
{
  const int t = blockIdx.y;
  const float* src = (t==0)?s0:(t==1)?s1:(t==2)?s2:(t==3)?s3:(t==4)?s4:(t==5)?s5:s6;
  __bf16*      dst = (t==0)?d0:(t==1)?d1:(t==2)?d2:(t==3)?d3:(t==4)?d4:(t==5)?d5:d6;
  const int nu = (t < 3) ? (M_*D_/8) : (D_*D_/8);   // 8-element units
  const int stride = gridDim.x * 256;
  for (int u = blockIdx.x*256 + threadIdx.x; u < nu; u += stride) {
    const float4* p = (const float4*)src + (size_t)u*2;
    float4 x0 = p[0], x1 = p[1];
    *(bf16x8*)(dst + (size_t)u*8) = cvt8(x0, x1);
  }
}

// ---------------------------------------------------------------------------
// K / Vt global layouts (chunk-major, XOR-swizzled row-major):
//   K  chunk c: elem(key,dk) at c*4096 + key*64 + (dk  ^ ((key&7)<<3))
//   Vt chunk c: elem(d,key)  at c*4096 + d*64   + (key ^ ((d  &7)<<3))
// ---------------------------------------------------------------------------

// ---------------------------------------------------------------------------
// Kernel 1: QKV projection, 128x64 tile, BK=32, bf16 inputs staged via
// global_load_lds into linear LDS, double-buffered.  (harness-verified,
// unchanged.)  grid = (M/128, D/64, 3).
// ---------------------------------------------------------------------------
__global__ __launch_bounds__(256) void proj_qkv(
    const __bf16* __restrict__ Xq, const __bf16* __restrict__ Xk,
    const __bf16* __restrict__ Xv,
    const __bf16* __restrict__ Wqb, const __bf16* __restrict__ Wkb,
    const __bf16* __restrict__ Wvb,
    const float* __restrict__ bq, const float* __restrict__ bk,
    const float* __restrict__ bv,
    __bf16* __restrict__ Qb, __bf16* __restrict__ Kb, __bf16* __restrict__ Vtb)
{
  __shared__ __align__(16) __bf16 smem[12288];

  const int z = blockIdx.z;
  const __bf16* X = (z==0) ? Xq  : (z==1) ? Xk  : Xv;
  const __bf16* W = (z==0) ? Wqb : (z==1) ? Wkb : Wvb;
  const float* bias = (z==0) ? bq : (z==1) ? bk : bv;

  const int m0 = blockIdx.x * 128;
  const int n0 = blockIdx.y * 64;      // == head*64
  const int tid  = threadIdx.x;
  const int w    = tid >> 6;
  const int lane = tid & 63;
  const int lcol = lane & 15;
  const int quad = lane >> 4;

  auto stage = [&](int bsel, int k0) {
#pragma unroll
    for (int j = 0; j < 2; ++j) {
      const int u = j*256 + tid;               // 16 B unit
      const int row = u >> 2, c8 = (u & 3)*8;
      load_lds16(X + (size_t)(m0 + row)*D_ + k0 + c8,
                 smem + bsel*4096 + u*8);
    }
    {
      const int u = tid;
      const int row = u >> 2, c8 = (u & 3)*8;
      load_lds16(W + (size_t)(n0 + row)*D_ + k0 + c8,
                 smem + 8192 + bsel*2048 + u*8);
    }
  };

  floatx4 zero = {0.f,0.f,0.f,0.f};
  floatx4 acc[2][4] = {{zero,zero,zero,zero},{zero,zero,zero,zero}};

  stage(0, 0);
  for (int it = 0; it < 16; ++it) {
    __syncthreads();                            // drains vmcnt: buf(it&1) ready
    if (it + 1 < 16) stage((it+1)&1, (it+1)*32);
    const __bf16* ab = smem + (it&1)*4096;
    const __bf16* bb = smem + 8192 + (it&1)*2048;
    bf16x8 af[2], bf[4];
#pragma unroll
    for (int mr = 0; mr < 2; ++mr)
      af[mr] = *(const bf16x8*)(ab + (w*32 + mr*16 + lcol)*32 + quad*8);
#pragma unroll
    for (int nt = 0; nt < 4; ++nt)
      bf[nt] = *(const bf16x8*)(bb + (nt*16 + lcol)*32 + quad*8);
#pragma unroll
    for (int mr = 0; mr < 2; ++mr)
#pragma unroll
      for (int nt = 0; nt < 4; ++nt)
        acc[mr][nt] = MFMA16x16x32(af[mr], bf[nt], acc[mr][nt]);
  }

  // ---- epilogue: scatter C frags into smem[0,8192) in output layout ----
  __syncthreads();
#pragma unroll
  for (int mr = 0; mr < 2; ++mr) {
#pragma unroll
    for (int nt = 0; nt < 4; ++nt) {
      const int dk = nt*16 + lcol;             // n & 63 (n0 head-aligned)
      const float bias_n = bias[n0 + dk];
#pragma unroll
      for (int r = 0; r < 4; ++r) {
        const int row = w*32 + mr*16 + quad*4 + r;   // m & 127
        const int klo = row & 63, ch = row >> 6;
        const float val = acc[mr][nt][r] + bias_n;
        int off;
        if (z == 0) {
          off = row*64 + dk;                                    // Q plain
        } else if (z == 1) {
          off = ch*4096 + klo*64 + (dk ^ ((klo & 7) << 3));     // K swz
        } else {
          off = ch*4096 + dk*64 + (klo ^ ((dk & 7) << 3));      // Vt swz
        }
        smem[off] = (__bf16)val;
      }
    }
  }
  __syncthreads();

  // ---- coalesced copy-out: one contiguous 16 KB piece ----
  __bf16* dst = (z==0) ? Qb : (z==1) ? Kb : Vtb;
  const int bb2 = m0 >> 11;            // batch
  const int hh  = n0 >> 6;             // head
  const size_t base = ((size_t)(bb2*H_ + hh))*(S_*DK_) + (size_t)(m0 & 2047)*64;
#pragma unroll
  for (int i = 0; i < 4; ++i) {
    const int u = i*256 + tid;         // 16B unit, 0..1023
    *(bf16x8*)(dst + base + u*8) = *(const bf16x8*)(smem + u*8);
  }
}

// ---------------------------------------------------------------------------
// Kernel 2: causal attention, swapped-QK 32x32, 2 WAVE-GROUPS per block.
// 512 threads: group g (waves 4g..4g+3) processes chunks c = 2i+g with its
// own 32 KB K/V double-buffer.  nc = 2t+2 is always EVEN -> both groups
// execute identical barrier counts (lockstep-safe __syncthreads).
// Two chunks retire per barrier step (critical path halved vs round 7) and
// 8 waves/CU hide latency.  End: group 1 spills partial O (fp32) + L via
// LDS; group 0 combines, normalizes, writes final O to attnb.
// grid = (16, H, B); LDS 64 KB.
// ---------------------------------------------------------------------------
__global__ __launch_bounds__(512) void attn_fwd(
    const __bf16* __restrict__ Qb, const __bf16* __restrict__ Kb,
    const __bf16* __restrict__ Vtb, __bf16* __restrict__ attnb)
{
  __shared__ __align__(16) __bf16 smem[32768];   // 64 KB
  char* base = (char*)smem;

  const int tid  = threadIdx.x;
  const int g    = tid >> 8;           // wave-group 0/1
  const int gt   = tid & 255;          // id within group
  const int w4   = gt >> 6;            // wave within group 0..3
  const int lane = tid & 63;
  const int l31  = lane & 31;
  const int hi   = lane >> 5;
  const int hh = blockIdx.y;
  const int bb = blockIdx.z;

  const int t  = 15 - blockIdx.x;      // heavy tiles dispatch first
  const int nc = 2*t + 2;              // even; chunks cover keys <= q_max
  const int nhalf = nc >> 1;           // iterations per group

  const int qr0    = t*128 + w4*32;
  const int q_lane = qr0 + l31;

  const __bf16* Qp = Qb  + (size_t)(bb*H_ + hh) * S_ * DK_;
  const __bf16* Kp = Kb  + (size_t)(bb*H_ + hh) * S_ * DK_;
  const __bf16* Vp = Vtb + (size_t)(bb*H_ + hh) * DK_ * S_;

  // Q as B-operand fragments: lane holds Q[q=l31][ks*16 + hi*8 + j]
  bf16x8 qf[4];
#pragma unroll
  for (int ks = 0; ks < 4; ++ks)
    qf[ks] = *(const bf16x8*)(Qp + (size_t)q_lane*DK_ + ks*16 + hi*8);

  floatx16 o0 = (floatx16)0.f, o1 = (floatx16)0.f;  // O[q][d<32], O[q][d>=32]
  float lsum = 0.f;

  // group-private K/V double buffers:
  //   kbufs [0, 32768): g*16384 + bsel*8192
  //   vbufs [32768, 65536): 32768 + g*16384 + bsel*8192
  auto stage_chunk = [&](int bsel, int c) {
    const char* ksrc = (const char*)(Kp + (size_t)c * 4096);
    const char* vsrc = (const char*)(Vp + (size_t)c * 4096);
    char* kd = base + g*16384 + bsel*8192;
    char* vd = base + 32768 + g*16384 + bsel*8192;
#pragma unroll
    for (int j = 0; j < 2; ++j) {
      const int off = j*4096 + gt*16;
      load_lds16(ksrc + off, kd + off);
      load_lds16(vsrc + off, vd + off);
    }
  };

  auto mkpa = [&](float a0,float a1,float a2,float a3,
                  float b0,float b1,float b2,float b3) -> bf16x8 {
    unsigned x0,x1,y0,y1;
    asm("v_cvt_pk_bf16_f32 %0, %1, %2" : "=v"(x0) : "v"(a0), "v"(a1));
    asm("v_cvt_pk_bf16_f32 %0, %1, %2" : "=v"(x1) : "v"(a2), "v"(a3));
    asm("v_cvt_pk_bf16_f32 %0, %1, %2" : "=v"(y0) : "v"(b0), "v"(b1));
    asm("v_cvt_pk_bf16_f32 %0, %1, %2" : "=v"(y1) : "v"(b2), "v"(b3));
    asm("v_permlane32_swap_b32 %0, %1" : "+v"(x0), "+v"(y0));
    asm("v_permlane32_swap_b32 %0, %1" : "+v"(x1), "+v"(y1));
    union { unsigned u[4]; bf16x8 v; } r;
    r.u[0] = x0; r.u[1] = x1; r.u[2] = y0; r.u[3] = y1;
    return r.v;
  };

  const float SC = 0.18033688011112042f;   // log2(e)/sqrt(DK)

  stage_chunk(0, g);                       // group g's first chunk = g
  for (int i = 0; i < nhalf; ++i) {
    __syncthreads();                       // both groups' chunks staged
    const int c = 2*i + g;
    if (c + 2 < nc) stage_chunk((i + 1)&1, c + 2);
    const int bsel = i & 1;
    const __bf16* kb = (const __bf16*)(base + g*16384 + bsel*8192);
    const __bf16* vb = (const __bf16*)(base + 32768 + g*16384 + bsel*8192);

    if (c*64 <= qr0 + 31) {                // wave has unmasked work here
      // ---- QK^T swapped: s[key][q], key blocks 0/1 ----
      floatx16 s0 = (floatx16)0.f, s1 = (floatx16)0.f;
#pragma unroll
      for (int ks = 0; ks < 4; ++ks) {
        const int csw = (ks*16 + hi*8) ^ ((l31 & 7) << 3);
        bf16x8 kf0 = *(const bf16x8*)(kb + l31*64 + csw);
        bf16x8 kf1 = *(const bf16x8*)(kb + (32 + l31)*64 + csw);
        s0 = MFMA32x32x16(kf0, qf[ks], s0);
        s1 = MFMA32x32x16(kf1, qf[ks], s1);
      }

      // ---- softmax (no max subtraction; scores O(1)) + causal mask ----
      const bool edge = (c*64 + 63 > qr0);
      if (edge) {
#pragma unroll
        for (int r = 0; r < 16; ++r) {
          const int koff = 8*(r>>2) + 4*hi + (r&3);
          float v0 = exp2f(s0[r] * SC);
          float v1 = exp2f(s1[r] * SC);
          s0[r] = (c*64 + koff      <= q_lane) ? v0 : 0.f;
          s1[r] = (c*64 + 32 + koff <= q_lane) ? v1 : 0.f;
        }
      } else {
#pragma unroll
        for (int r = 0; r < 16; ++r) {
          s0[r] = exp2f(s0[r] * SC);
          s1[r] = exp2f(s1[r] * SC);
        }
      }
#pragma unroll
      for (int r = 0; r < 16; ++r) lsum += s0[r] + s1[r];

      bf16x8 pa[4];
      pa[0] = mkpa(s0[0],s0[1],s0[2],s0[3],s0[4],s0[5],s0[6],s0[7]);
      pa[1] = mkpa(s0[8],s0[9],s0[10],s0[11],s0[12],s0[13],s0[14],s0[15]);
      pa[2] = mkpa(s1[0],s1[1],s1[2],s1[3],s1[4],s1[5],s1[6],s1[7]);
      pa[3] = mkpa(s1[8],s1[9],s1[10],s1[11],s1[12],s1[13],s1[14],s1[15]);

      // ---- PV: O += P * V  (B-frags from swizzled Vt tile) ----
#pragma unroll
      for (int ks = 0; ks < 4; ++ks) {
        const int csw0 = (ks*16 + hi*8) ^ ((l31 & 7) << 3);
        bf16x8 vf0 = *(const bf16x8*)(vb + l31*64 + csw0);
        bf16x8 vf1 = *(const bf16x8*)(vb + (32 + l31)*64 + csw0);
        o0 = MFMA32x32x16(pa[ks], vf0, o0);
        o1 = MFMA32x32x16(pa[ks], vf1, o1);
      }
    }
  }

  // ---- combine the two groups' partials, normalize, write attnb ----
  __syncthreads();                          // all waves done with K/V bufs
  const float lpart = lsum + __shfl_xor(lsum, 32);   // per q=l31, both halves

  float* O1 = (float*)base;                 // [128][64] fp32 (32 KB)
  float* L1 = (float*)(base + 32768);       // 128 f32
  float* Lc = (float*)(base + 33792);       // 128 f32 (combined)
  __bf16* ob = (__bf16*)(base + 36864);     // [128][64] bf16 (16 KB)

  if (g == 1) {
#pragma unroll
    for (int r = 0; r < 16; ++r) {
      const int qloc = 8*(r>>2) + 4*hi + (r&3);
      O1[(w4*32 + qloc)*64 + l31]      = o0[r];
      O1[(w4*32 + qloc)*64 + 32 + l31] = o1[r];
    }
    if (lane < 32) L1[w4*32 + l31] = lpart;
  }
  __syncthreads();                          // O1/L1 visible

  if (g == 0) {
    if (lane < 32) Lc[w4*32 + l31] = lpart + L1[w4*32 + l31];
  }
  __syncthreads();                          // Lc visible

  if (g == 0) {
#pragma unroll
    for (int r = 0; r < 16; ++r) {
      const int qloc = 8*(r>>2) + 4*hi + (r&3);
      const float rinv = 1.0f / Lc[w4*32 + qloc];
      const float t0 = o0[r] + O1[(w4*32 + qloc)*64 + l31];
      const float t1 = o1[r] + O1[(w4*32 + qloc)*64 + 32 + l31];
      ob[(w4*32 + qloc)*64 + l31]      = (__bf16)(t0 * rinv);
      ob[(w4*32 + qloc)*64 + 32 + l31] = (__bf16)(t1 * rinv);
    }
  }
  __syncthreads();                          // ob ready

  // coalesced copy to attnb [B,S,D]: 128 rows x 128 B (this head's column)
  __bf16* adst = attnb + ((size_t)(bb*S_ + t*128))*D_ + hh*DK_;
#pragma unroll
  for (int i = 0; i < 2; ++i) {
    const int u = i*512 + tid;              // 16 B unit, 0..1023
    const int row = u >> 3, grp = u & 7;
    *(bf16x8*)(adst + (size_t)row*D_ + grp*8) = *(const bf16x8*)(ob + u*8);
  }
}

// ---------------------------------------------------------------------------
// Kernel 3: output projection — pure GEMM, 128x64 tile, BK=32, both operands
// via global_load_lds, direct fp32 C-write.  (harness-verified, unchanged.)
// grid = (M/128, D/64) = 256 blocks.
// ---------------------------------------------------------------------------
__global__ __launch_bounds__(256) void proj_out(
    const __bf16* __restrict__ attnb, const __bf16* __restrict__ Wob,
    const float* __restrict__ bo, float* __restrict__ out)
{
  __shared__ __align__(16) __bf16 smem[12288];

  const int m0 = blockIdx.x * 128;
  const int n0 = blockIdx.y * 64;
  const int tid  = threadIdx.x;
  const int w    = tid >> 6;
  const int lane = tid & 63;
  const int lcol = lane & 15;
  const int quad = lane >> 4;

  auto stage = [&](int bsel, int k0) {
#pragma unroll
    for (int j = 0; j < 2; ++j) {
      const int u = j*256 + tid;               // 16 B unit
      const int row = u >> 2, c8 = (u & 3)*8;
      load_lds16(attnb + (size_t)(m0 + row)*D_ + k0 + c8,
                 smem + bsel*4096 + u*8);
    }
    {
      const int u = tid;
      const int row = u >> 2, c8 = (u & 3)*8;
      load_lds16(Wob + (size_t)(n0 + row)*D_ + k0 + c8,
                 smem + 8192 + bsel*2048 + u*8);
    }
  };

  floatx4 zero = {0.f,0.f,0.f,0.f};
  floatx4 acc[2][4] = {{zero,zero,zero,zero},{zero,zero,zero,zero}};

  stage(0, 0);
  for (int it = 0; it < 16; ++it) {
    __syncthreads();                            // drains vmcnt: buf(it&1) ready
    if (it + 1 < 16) stage((it+1)&1, (it+1)*32);
    const __bf16* ab = smem + (it&1)*4096;
    const __bf16* bb = smem + 8192 + (it&1)*2048;
    bf16x8 af[2], bf[4];
#pragma unroll
    for (int mr = 0; mr < 2; ++mr)
      af[mr] = *(const bf16x8*)(ab + (w*32 + mr*16 + lcol)*32 + quad*8);
#pragma unroll
    for (int nt = 0; nt < 4; ++nt)
      bf[nt] = *(const bf16x8*)(bb + (nt*16 + lcol)*32 + quad*8);
#pragma unroll
    for (int mr = 0; mr < 2; ++mr)
#pragma unroll
      for (int nt = 0; nt < 4; ++nt)
        acc[mr][nt] = MFMA16x16x32(af[mr], bf[nt], acc[mr][nt]);
  }

  // direct C-write: fp32, 64 B contiguous per 16-lane group
#pragma unroll
  for (int mr = 0; mr < 2; ++mr) {
#pragma unroll
    for (int nt = 0; nt < 4; ++nt) {
      const int n = n0 + nt*16 + lcol;
      const float bias_n = bo[n];
#pragma unroll
      for (int r = 0; r < 4; ++r) {
        const int row = w*32 + mr*16 + quad*4 + r;
        out[(size_t)(m0 + row) * D_ + n] = acc[mr][nt][r] + bias_n;
      }
    }
  }
}

// ---------------------------------------------------------------------------
extern "C" void kernel_launch(void* const* d_in, const int* in_sizes, int n_in,
                              void* d_out, int out_size, void* d_ws, size_t ws_size,
                              hipStream_t stream) {
  const float* q_in = (const float*)d_in[0];
  const float* k_in = (const float*)d_in[1];
  const float* v_in = (const float*)d_in[2];
  // d_in[3] = mask (causal tril) — implied by the kernel, unused
  const float* Wq = (const float*)d_in[4];
  const float* bq = (const float*)d_in[5];
  const float* Wk = (const float*)d_in[6];
  const float* bk = (const float*)d_in[7];
  const float* Wv = (const float*)d_in[8];
  const float* bv = (const float*)d_in[9];
  const float* Wo = (const float*)d_in[10];
  const float* bo = (const float*)d_in[11];
  float* out = (float*)d_out;

  __bf16* ws    = (__bf16*)d_ws;
  __bf16* Qb    = ws;                  // [B,H,S,DK] plain
  __bf16* Kb    = ws + 1*2097152;      // chunk-major, swizzled
  __bf16* Vtb   = ws + 2*2097152;      // chunk-major, swizzled (transposed)
  __bf16* attnb = ws + 3*2097152;      // [B,S,D] final attention output

  // bf16 copies of inputs (written by cvt_inputs each launch)
  __bf16* Xqb = ws + 4*2097152;
  __bf16* Xkb = Xqb + 2097152;
  __bf16* Xvb = Xkb + 2097152;
  __bf16* Wqb = Xvb + 2097152;
  __bf16* Wkb = Wqb + 262144;
  __bf16* Wvb = Wkb + 262144;
  __bf16* Wob = Wvb + 262144;

  cvt_inputs<<<dim3(512, 7, 1), dim3(256), 0, stream>>>(
      q_in, k_in, v_in, Wq, Wk, Wv, Wo,
      Xqb, Xkb, Xvb, Wqb, Wkb, Wvb, Wob);

  proj_qkv<<<dim3(M_/128, D_/64, 3), dim3(256), 0, stream>>>(
      Xqb, Xkb, Xvb, Wqb, Wkb, Wvb, bq, bk, bv, Qb, Kb, Vtb);

  attn_fwd<<<dim3(16, H_, B_), dim3(512), 0, stream>>>(
      Qb, Kb, Vtb, attnb);

  proj_out<<<dim3(M_/128, D_/64), dim3(256), 0, stream>>>(
      attnb, Wob, bo, out);
}